// Round 7
// baseline (140.140 us; speedup 1.0000x reference)
//
#include <hip/hip_runtime.h>
#include <cstdint>

#define DEV static __device__ __forceinline__

typedef __attribute__((__ext_vector_type__(8))) __bf16 bf16x8;
typedef __attribute__((__ext_vector_type__(4))) float f32x4;

static constexpr int Bc = 16, Sc = 2048, Dc = 1024;

DEV unsigned short f2bf(float x) {
  unsigned int u = __float_as_uint(x);
  unsigned int r = (u + 0x7fffu + ((u >> 16) & 1u)) >> 16;
  return (unsigned short)r;
}
DEV unsigned int pack2(float a, float b) {
  return (unsigned int)f2bf(a) | ((unsigned int)f2bf(b) << 16);
}
DEV float tanh_fast(float x) {
  return 1.f - 2.f / (__expf(2.f * x) + 1.f);
}
DEV void gload16(const void* g, void* l) {
  __builtin_amdgcn_global_load_lds(
      (const __attribute__((address_space(1))) unsigned int*)g,
      (__attribute__((address_space(3))) unsigned int*)l, 16, 0, 0);
}

// ---- kernel 1: enc fp32 -> bf16, skipping masked rows (s >= len[b]).
__global__ __launch_bounds__(256) void k_cvt_enc(const float* __restrict__ in,
                                                 unsigned short* __restrict__ out,
                                                 const int* __restrict__ lengths) {
  int team = threadIdx.x >> 7;  // 0..1
  int lane = threadIdx.x & 127;
  int r0 = blockIdx.x * 16;
  int b = r0 >> 11;
  int len = lengths[b];
  for (int rr = team; rr < 16; rr += 2) {
    int s = (r0 + rr) & 2047;
    if (s >= len) continue;
    const float* src = in + (size_t)(r0 + rr) * Dc + lane * 8;
    unsigned short* dst = out + (size_t)(r0 + rr) * Dc + lane * 8;
    float4 f0 = *(const float4*)src;
    float4 f1 = *(const float4*)(src + 4);
    uint4 o;
    o.x = pack2(f0.x, f0.y);
    o.y = pack2(f0.z, f0.w);
    o.z = pack2(f1.x, f1.y);
    o.w = pack2(f1.z, f1.w);
    *(uint4*)dst = o;
  }
}

// ---- kernel 2: We[e,d] = W[e, D+d] -> bf16 (2 MB out)
__global__ __launch_bounds__(256) void k_cvt_We(const float* __restrict__ W,
                                                unsigned short* __restrict__ out) {
  int i = (blockIdx.x * 256 + threadIdx.x) * 8;
  int e = i >> 10, d = i & 1023;
  const float* p = W + (size_t)e * 2048 + 1024 + d;
  float4 f0 = *(const float4*)p;
  float4 f1 = *(const float4*)(p + 4);
  uint4 o;
  o.x = pack2(f0.x, f0.y);
  o.y = pack2(f0.z, f0.w);
  o.z = pack2(f1.x, f1.y);
  o.w = pack2(f1.z, f1.w);
  *(uint4*)(out + i) = o;
}

// ---- kernel 3: hid_proj[b,e] = bias[e] + sum_d hidden[b,d]*W[e,d]
__global__ __launch_bounds__(256) void k_hidproj(const float* __restrict__ hidden,
                                                 const float* __restrict__ W,
                                                 const float* __restrict__ bias,
                                                 float* __restrict__ hp) {
  __shared__ float wrow[Dc];
  int e = blockIdx.x, t = threadIdx.x;
  for (int i = t; i < Dc; i += 256) wrow[i] = W[(size_t)e * 2048 + i];
  __syncthreads();
  int w = t >> 6, lane = t & 63;
  float bv = bias[e];
  for (int bi = w; bi < Bc; bi += 4) {
    float s = 0.f;
    const float* hrow = hidden + (size_t)bi * Dc;
    for (int d = lane; d < Dc; d += 64) s += hrow[d] * wrow[d];
    for (int m = 1; m < 64; m <<= 1) s += __shfl_xor(s, m);
    if (lane == 0) hp[(size_t)bi * Dc + e] = s + bv;
  }
}

// ---- kernel 3b: compact active panels into a worklist (1 block).
// wl[0] = count; wl[1+i] = (b<<8)|sblk; wl[320] = work cursor (zeroed here,
// so every kernel_launch invocation is self-contained/deterministic).
__global__ __launch_bounds__(256) void k_worklist(const int* __restrict__ lengths,
                                                  int* __restrict__ wl) {
  int t = threadIdx.x;  // t = sblk*16 + b
  int sblk = t >> 4, b = t & 15;
  int active = (sblk * 128 < lengths[b]) ? 1 : 0;
  unsigned long long mask = __ballot(active);
  int lane = t & 63, wid = t >> 6;
  int prefix = __popcll(mask & ((1ull << lane) - 1ull));
  __shared__ int woff[4];
  if (lane == 0) woff[wid] = __popcll(mask);
  __syncthreads();
  int base = 0;
  for (int i = 0; i < wid; i++) base += woff[i];
  if (active) wl[1 + base + prefix] = (b << 8) | sblk;
  if (t == 0) {
    wl[0] = woff[0] + woff[1] + woff[2] + woff[3];
    wl[320] = 0;  // work-stealing cursor
  }
}

// ---- kernel 4: scores GEMM (bf16 MFMA) + tanh + v-dot, per-e-tile partials.
// Round-2 body wrapped in a PERSISTENT work-stealing loop: thread 0 grabs the
// next item via atomicAdd on a global cursor, broadcasts via LDS. Every
// resident block stays busy until the item pool drains -> no dispatch-slot
// imbalance, no tail (the no-backfill problem of instant-exit blocks).
// Items write disjoint pscores slices, so output is deterministic regardless
// of which block processes which item.
__global__ __launch_bounds__(256) void k_scores(const unsigned short* __restrict__ Ae,
                                                const unsigned short* __restrict__ We,
                                                const float* __restrict__ hp,
                                                const float* __restrict__ v,
                                                int* __restrict__ wl,
                                                float* __restrict__ pscores) {
  __shared__ unsigned short As[128 * 32];
  __shared__ unsigned short Bs[128 * 32];
  __shared__ float hp_s[128], v_s[128], sc_s[128];
  __shared__ int cur_s;

  int t = threadIdx.x;
  int w = t >> 6, lane = t & 63;
  int total = wl[0] * 8;

  for (;;) {
    if (t == 0) cur_s = atomicAdd(&wl[320], 1);
    __syncthreads();
    int idx = cur_s;
    if (idx >= total) return;
    int g = idx >> 3, et = idx & 7;
    int pk = wl[1 + g];
    int b = pk >> 8, sblk = pk & 255;
    int s0 = sblk * 128;
    int m0 = b * Sc + s0;
    int e0 = et * 128;

    if (t < 128) {
      hp_s[t] = hp[(size_t)b * Dc + e0 + t];
      v_s[t] = v[e0 + t];
      sc_s[t] = 0.f;
    }

    f32x4 acc[4][4] = {};
    int wr = w >> 1, wc = w & 1;
    const unsigned short* Ab = Ae + (size_t)m0 * Dc;
    const unsigned short* Bb = We + (size_t)e0 * Dc;
    int trow = t >> 2, tcol = (t & 3) * 8;

    for (int k0 = 0; k0 < Dc; k0 += 32) {
      const unsigned short* ga = Ab + (size_t)trow * Dc + k0 + tcol;
      const unsigned short* gb = Bb + (size_t)trow * Dc + k0 + tcol;
      gload16(ga, As + w * 512);
      gload16(ga + 64 * Dc, As + 2048 + w * 512);
      gload16(gb, Bs + w * 512);
      gload16(gb + 64 * Dc, Bs + 2048 + w * 512);
      __syncthreads();
      int kc = (lane >> 4) * 8;
      int ar = (wr * 64 + (lane & 15)) * 32 + kc;
      int br = (wc * 64 + (lane & 15)) * 32 + kc;
      bf16x8 af[4], bfr[4];
      for (int m = 0; m < 4; m++)
        af[m] = __builtin_bit_cast(bf16x8, *(const uint4*)(As + ar + m * 512));
      for (int n = 0; n < 4; n++)
        bfr[n] = __builtin_bit_cast(bf16x8, *(const uint4*)(Bs + br + n * 512));
      for (int m = 0; m < 4; m++)
        for (int n = 0; n < 4; n++)
          acc[m][n] = __builtin_amdgcn_mfma_f32_16x16x32_bf16(af[m], bfr[n], acc[m][n], 0, 0, 0);
      __syncthreads();
    }

    // epilogue: rowsum_e( v[e] * tanh(acc + hp[e]) )
    for (int m = 0; m < 4; m++) {
      float rs0 = 0.f, rs1 = 0.f, rs2 = 0.f, rs3 = 0.f;
      for (int n = 0; n < 4; n++) {
        int ec = wc * 64 + n * 16 + (lane & 15);
        float hpv = hp_s[ec], vv = v_s[ec];
        f32x4 a = acc[m][n];
        rs0 += vv * tanh_fast(a[0] + hpv);
        rs1 += vv * tanh_fast(a[1] + hpv);
        rs2 += vv * tanh_fast(a[2] + hpv);
        rs3 += vv * tanh_fast(a[3] + hpv);
      }
      for (int mask = 1; mask < 16; mask <<= 1) {
        rs0 += __shfl_xor(rs0, mask);
        rs1 += __shfl_xor(rs1, mask);
        rs2 += __shfl_xor(rs2, mask);
        rs3 += __shfl_xor(rs3, mask);
      }
      if ((lane & 15) == 0) {  // exactly 2 adders per row (wc=0,1): deterministic
        int rbase = wr * 64 + m * 16 + (lane >> 4) * 4;
        atomicAdd(&sc_s[rbase + 0], rs0);
        atomicAdd(&sc_s[rbase + 1], rs1);
        atomicAdd(&sc_s[rbase + 2], rs2);
        atomicAdd(&sc_s[rbase + 3], rs3);
      }
    }
    __syncthreads();
    if (t < 128) pscores[((size_t)et * Bc + b) * Sc + s0 + t] = sc_s[t];
    // next item: cur_s rewrite is ordered by the loop-top __syncthreads();
    // sc_s[t] rewrite races only with its own thread's read above.
  }
}

// ---- kernel 5: masked softmax over S per batch; sums 8 e-tile partials
__global__ __launch_bounds__(256) void k_softmax(const float* __restrict__ pscores,
                                                 const int* __restrict__ lengths,
                                                 float* __restrict__ attn) {
  int b = blockIdx.x, t = threadIdx.x;
  int len = lengths[b];
  float vals[8];
  float mx = -INFINITY;
  for (int i = 0; i < 8; i++) {
    int s = t + i * 256;
    float sc = 0.f;
    for (int p = 0; p < 8; p++) sc += pscores[((size_t)p * Bc + b) * Sc + s];
    sc = (s < len) ? sc : -INFINITY;
    vals[i] = sc;
    mx = fmaxf(mx, sc);
  }
  for (int m = 1; m < 64; m <<= 1) mx = fmaxf(mx, __shfl_xor(mx, m));
  __shared__ float rmax[4], rsum[4];
  int w = t >> 6, lane = t & 63;
  if (lane == 0) rmax[w] = mx;
  __syncthreads();
  mx = fmaxf(fmaxf(rmax[0], rmax[1]), fmaxf(rmax[2], rmax[3]));
  float sm = 0.f;
  for (int i = 0; i < 8; i++) {
    vals[i] = __expf(vals[i] - mx);
    sm += vals[i];
  }
  for (int m = 1; m < 64; m <<= 1) sm += __shfl_xor(sm, m);
  if (lane == 0) rsum[w] = sm;
  __syncthreads();
  sm = rsum[0] + rsum[1] + rsum[2] + rsum[3];
  float inv = 1.f / sm;
  for (int i = 0; i < 8; i++) attn[(size_t)b * Sc + t + i * 256] = vals[i] * inv;
}

// ---- kernel 6: context partials from bf16 enc (half the traffic of fp32)
__global__ __launch_bounds__(256) void k_ctx(const unsigned short* __restrict__ ebf,
                                             const float* __restrict__ attn,
                                             const int* __restrict__ lengths,
                                             float* __restrict__ pctx) {
  int b = blockIdx.x >> 4, sp = blockIdx.x & 15;
  int t = threadIdx.x;
  int d0 = t * 4;
  int sbeg = sp * 128;
  float* outp = pctx + ((size_t)sp * Bc + b) * Dc + d0;
  int len = lengths[b];
  if (sbeg >= len) {
    *(float4*)outp = make_float4(0.f, 0.f, 0.f, 0.f);
    return;
  }
  __shared__ float at_s[128];
  if (t < 128) at_s[t] = attn[(size_t)b * Sc + sbeg + t];
  __syncthreads();
  float4 a = make_float4(0.f, 0.f, 0.f, 0.f);
  const unsigned short* ebase = ebf + ((size_t)b * Sc + sbeg) * Dc + d0;
  int ns = min(128, len - sbeg);
  for (int i = 0; i < ns; i++) {
    float wt = at_s[i];
    uint2 u = *(const uint2*)(ebase + (size_t)i * Dc);
    a.x += wt * __uint_as_float(u.x << 16);
    a.y += wt * __uint_as_float(u.x & 0xffff0000u);
    a.z += wt * __uint_as_float(u.y << 16);
    a.w += wt * __uint_as_float(u.y & 0xffff0000u);
  }
  *(float4*)outp = a;
}

// ---- kernel 7: reduce 16 context partials -> out (B,1,D)
__global__ __launch_bounds__(256) void k_reduce(const float* __restrict__ pctx,
                                               float* __restrict__ out) {
  int i = blockIdx.x * 256 + threadIdx.x;
  int b = i >> 10, d = i & 1023;
  float s = 0.f;
  for (int p = 0; p < 16; p++) s += pctx[((size_t)p * Bc + b) * Dc + d];
  out[i] = s;
}

extern "C" void kernel_launch(void* const* d_in, const int* in_sizes, int n_in,
                              void* d_out, int out_size, void* d_ws, size_t ws_size,
                              hipStream_t stream) {
  const float* enc = (const float*)d_in[0];
  const float* hidden = (const float*)d_in[1];
  const int* lengths = (const int*)d_in[2];
  const float* W = (const float*)d_in[3];
  const float* bias = (const float*)d_in[4];
  const float* v = (const float*)d_in[5];
  float* out = (float*)d_out;

  char* ws = (char*)d_ws;
  unsigned short* ebf = (unsigned short*)ws;
  unsigned short* webf = (unsigned short*)(ws + 67108864);
  float* hp = (float*)(ws + 69206016);
  float* pscores = (float*)(ws + 69271552);
  float* attn = (float*)(ws + 70320128);
  float* pctx = (float*)(ws + 70451200);
  int* wl = (int*)(ws + 70516736);  // wl[0..256] worklist, wl[320] cursor

  hipLaunchKernelGGL(k_cvt_enc, dim3(2048), dim3(256), 0, stream, enc, ebf, lengths);
  hipLaunchKernelGGL(k_cvt_We, dim3(512), dim3(256), 0, stream, W, webf);
  hipLaunchKernelGGL(k_hidproj, dim3(1024), dim3(256), 0, stream, hidden, W, bias, hp);
  hipLaunchKernelGGL(k_worklist, dim3(1), dim3(256), 0, stream, lengths, wl);
  hipLaunchKernelGGL(k_scores, dim3(2048), dim3(256), 0, stream, ebf, webf, hp, v,
                     wl, pscores);
  hipLaunchKernelGGL(k_softmax, dim3(16), dim3(256), 0, stream, pscores, lengths, attn);
  hipLaunchKernelGGL(k_ctx, dim3(256), dim3(256), 0, stream, ebf, attn, lengths, pctx);
  hipLaunchKernelGGL(k_reduce, dim3(64), dim3(256), 0, stream, pctx, out);
}

// Round 8
// 116.979 us; speedup vs baseline: 1.1980x; 1.1980x over previous
//
#include <hip/hip_runtime.h>
#include <cstdint>

#define DEV static __device__ __forceinline__

typedef __attribute__((__ext_vector_type__(8))) __bf16 bf16x8;
typedef __attribute__((__ext_vector_type__(4))) float f32x4;

static constexpr int Bc = 16, Sc = 2048, Dc = 1024;

DEV unsigned short f2bf(float x) {
  unsigned int u = __float_as_uint(x);
  unsigned int r = (u + 0x7fffu + ((u >> 16) & 1u)) >> 16;
  return (unsigned short)r;
}
DEV unsigned int pack2(float a, float b) {
  return (unsigned int)f2bf(a) | ((unsigned int)f2bf(b) << 16);
}
DEV float tanh_fast(float x) {
  return 1.f - 2.f / (__expf(2.f * x) + 1.f);
}
DEV void gload16(const void* g, void* l) {
  __builtin_amdgcn_global_load_lds(
      (const __attribute__((address_space(1))) unsigned int*)g,
      (__attribute__((address_space(3))) unsigned int*)l, 16, 0, 0);
}

// ---- kernel 1: enc fp32 -> bf16, skipping masked rows (s >= len[b]).
__global__ __launch_bounds__(256) void k_cvt_enc(const float* __restrict__ in,
                                                 unsigned short* __restrict__ out,
                                                 const int* __restrict__ lengths) {
  int team = threadIdx.x >> 7;  // 0..1
  int lane = threadIdx.x & 127;
  int r0 = blockIdx.x * 16;
  int b = r0 >> 11;
  int len = lengths[b];
  for (int rr = team; rr < 16; rr += 2) {
    int s = (r0 + rr) & 2047;
    if (s >= len) continue;
    const float* src = in + (size_t)(r0 + rr) * Dc + lane * 8;
    unsigned short* dst = out + (size_t)(r0 + rr) * Dc + lane * 8;
    float4 f0 = *(const float4*)src;
    float4 f1 = *(const float4*)(src + 4);
    uint4 o;
    o.x = pack2(f0.x, f0.y);
    o.y = pack2(f0.z, f0.w);
    o.z = pack2(f1.x, f1.y);
    o.w = pack2(f1.z, f1.w);
    *(uint4*)dst = o;
  }
}

// ---- kernel 2: We[e,d] = W[e, D+d] -> bf16 (2 MB out)
__global__ __launch_bounds__(256) void k_cvt_We(const float* __restrict__ W,
                                                unsigned short* __restrict__ out) {
  int i = (blockIdx.x * 256 + threadIdx.x) * 8;
  int e = i >> 10, d = i & 1023;
  const float* p = W + (size_t)e * 2048 + 1024 + d;
  float4 f0 = *(const float4*)p;
  float4 f1 = *(const float4*)(p + 4);
  uint4 o;
  o.x = pack2(f0.x, f0.y);
  o.y = pack2(f0.z, f0.w);
  o.z = pack2(f1.x, f1.y);
  o.w = pack2(f1.z, f1.w);
  *(uint4*)(out + i) = o;
}

// ---- kernel 3: hid_proj[b,e] = bias[e] + sum_d hidden[b,d]*W[e,d]
__global__ __launch_bounds__(256) void k_hidproj(const float* __restrict__ hidden,
                                                 const float* __restrict__ W,
                                                 const float* __restrict__ bias,
                                                 float* __restrict__ hp) {
  __shared__ float wrow[Dc];
  int e = blockIdx.x, t = threadIdx.x;
  for (int i = t; i < Dc; i += 256) wrow[i] = W[(size_t)e * 2048 + i];
  __syncthreads();
  int w = t >> 6, lane = t & 63;
  float bv = bias[e];
  for (int bi = w; bi < Bc; bi += 4) {
    float s = 0.f;
    const float* hrow = hidden + (size_t)bi * Dc;
    for (int d = lane; d < Dc; d += 64) s += hrow[d] * wrow[d];
    for (int m = 1; m < 64; m <<= 1) s += __shfl_xor(s, m);
    if (lane == 0) hp[(size_t)bi * Dc + e] = s + bv;
  }
}

// ---- kernel 3b: compact active panels into a worklist (1 block).
// wl[0] = count; wl[1+i] = (b<<8)|sblk, sblk-major order.
__global__ __launch_bounds__(256) void k_worklist(const int* __restrict__ lengths,
                                                  int* __restrict__ wl) {
  int t = threadIdx.x;  // t = sblk*16 + b
  int sblk = t >> 4, b = t & 15;
  int active = (sblk * 128 < lengths[b]) ? 1 : 0;
  unsigned long long mask = __ballot(active);
  int lane = t & 63, wid = t >> 6;
  int prefix = __popcll(mask & ((1ull << lane) - 1ull));
  __shared__ int woff[4];
  if (lane == 0) woff[wid] = __popcll(mask);
  __syncthreads();
  int base = 0;
  for (int i = 0; i < wid; i++) base += woff[i];
  if (active) wl[1 + base + prefix] = (b << 8) | sblk;
  if (t == 0) wl[0] = woff[0] + woff[1] + woff[2] + woff[3];
}

// ---- kernel 4: scores GEMM (bf16 MFMA) + tanh + v-dot, per-e-tile partials.
// LDS-intensity rework: block tile 128(M) x 256(E), 4 waves, each wave spans
// full M with a 128x64 output tile (acc 8x4 f32x4). LDS traffic drops from
// 48 KB to 72 KB per *2x* FLOPs (34 vs 46 KB/MFLOP) and barrier count per
// FLOP halves -- attacks the measured LDS-BW ceiling of the 2-barrier loop.
// Work distribution: atomic-free uniform spread of worklist items over the
// 1024-block grid; et-major ordering puts a panel's 4 e-tile siblings exactly
// 256 blocks apart -> same bx%8 -> same XCD (A-panel L2 reuse preserved).
__global__ __launch_bounds__(256, 2) void k_scores(const unsigned short* __restrict__ Ae,
                                                   const unsigned short* __restrict__ We,
                                                   const float* __restrict__ hp,
                                                   const float* __restrict__ v,
                                                   const int* __restrict__ wl,
                                                   float* __restrict__ pscores) {
  int count = wl[0];
  int items = count * 4;
  int bx = blockIdx.x;
  int j_lo = (bx * items) >> 10;        // uniform spread over 1024 blocks
  int j_hi = ((bx + 1) * items) >> 10;  // j_hi - j_lo is 0 or 1
  if (j_lo >= j_hi) return;
  int et = j_lo / count;
  int g = j_lo - et * count;
  int pk = wl[1 + g];
  int b = pk >> 8, sblk = pk & 255;
  int s0 = sblk * 128;
  int m0 = b * Sc + s0;
  int e0 = et * 256;

  __shared__ unsigned short As[128 * 32];
  __shared__ unsigned short Bs[256 * 32];
  __shared__ float hp_s[256], v_s[256], sc_s[128];

  int t = threadIdx.x;
  int w = t >> 6, lane = t & 63;
  hp_s[t] = hp[(size_t)b * Dc + e0 + t];
  v_s[t] = v[e0 + t];
  if (t < 128) sc_s[t] = 0.f;

  f32x4 acc[8][4] = {};
  // staging source: thread t covers row (t>>2) (+64 per call), col (t&3)*8
  const unsigned short* gaT = Ae + (size_t)(m0 + (t >> 2)) * Dc + (t & 3) * 8;
  const unsigned short* gbT = We + (size_t)(e0 + (t >> 2)) * Dc + (t & 3) * 8;

  int kc = (lane >> 4) * 8;
  int ar = (lane & 15) * 32 + kc;
  int br = (w * 64 + (lane & 15)) * 32 + kc;

#pragma unroll 1
  for (int k0 = 0; k0 < Dc; k0 += 32) {
    gload16(gaT + k0, As + w * 512);
    gload16(gaT + k0 + 64 * Dc, As + 2048 + w * 512);
#pragma unroll
    for (int jj = 0; jj < 4; ++jj)
      gload16(gbT + k0 + jj * 64 * Dc, Bs + jj * 2048 + w * 512);
    __syncthreads();
    bf16x8 af[8], bfr[4];
#pragma unroll
    for (int m = 0; m < 8; m++)
      af[m] = __builtin_bit_cast(bf16x8, *(const uint4*)(As + ar + m * 512));
#pragma unroll
    for (int n = 0; n < 4; n++)
      bfr[n] = __builtin_bit_cast(bf16x8, *(const uint4*)(Bs + br + n * 512));
#pragma unroll
    for (int m = 0; m < 8; m++)
#pragma unroll
      for (int n = 0; n < 4; n++)
        acc[m][n] = __builtin_amdgcn_mfma_f32_16x16x32_bf16(af[m], bfr[n], acc[m][n], 0, 0, 0);
    __syncthreads();
  }

  // epilogue: rowsum over this wave's 64 e-cols of v[e]*tanh(acc + hp[e])
#pragma unroll
  for (int m = 0; m < 8; m++) {
    float rs0 = 0.f, rs1 = 0.f, rs2 = 0.f, rs3 = 0.f;
#pragma unroll
    for (int n = 0; n < 4; n++) {
      int ec = w * 64 + n * 16 + (lane & 15);
      float hpv = hp_s[ec], vv = v_s[ec];
      f32x4 a = acc[m][n];
      rs0 += vv * tanh_fast(a[0] + hpv);
      rs1 += vv * tanh_fast(a[1] + hpv);
      rs2 += vv * tanh_fast(a[2] + hpv);
      rs3 += vv * tanh_fast(a[3] + hpv);
    }
    for (int mask = 1; mask < 16; mask <<= 1) {
      rs0 += __shfl_xor(rs0, mask);
      rs1 += __shfl_xor(rs1, mask);
      rs2 += __shfl_xor(rs2, mask);
      rs3 += __shfl_xor(rs3, mask);
    }
    if ((lane & 15) == 0) {  // 4 adders per row (one per wave)
      int rbase = m * 16 + (lane >> 4) * 4;
      atomicAdd(&sc_s[rbase + 0], rs0);
      atomicAdd(&sc_s[rbase + 1], rs1);
      atomicAdd(&sc_s[rbase + 2], rs2);
      atomicAdd(&sc_s[rbase + 3], rs3);
    }
  }
  __syncthreads();
  if (t < 128) pscores[((size_t)et * Bc + b) * Sc + s0 + t] = sc_s[t];
}

// ---- kernel 5: masked softmax over S per batch; sums 4 e-tile partials
__global__ __launch_bounds__(256) void k_softmax(const float* __restrict__ pscores,
                                                 const int* __restrict__ lengths,
                                                 float* __restrict__ attn) {
  int b = blockIdx.x, t = threadIdx.x;
  int len = lengths[b];
  float vals[8];
  float mx = -INFINITY;
  for (int i = 0; i < 8; i++) {
    int s = t + i * 256;
    float sc = 0.f;
    for (int p = 0; p < 4; p++) sc += pscores[((size_t)p * Bc + b) * Sc + s];
    sc = (s < len) ? sc : -INFINITY;
    vals[i] = sc;
    mx = fmaxf(mx, sc);
  }
  for (int m = 1; m < 64; m <<= 1) mx = fmaxf(mx, __shfl_xor(mx, m));
  __shared__ float rmax[4], rsum[4];
  int w = t >> 6, lane = t & 63;
  if (lane == 0) rmax[w] = mx;
  __syncthreads();
  mx = fmaxf(fmaxf(rmax[0], rmax[1]), fmaxf(rmax[2], rmax[3]));
  float sm = 0.f;
  for (int i = 0; i < 8; i++) {
    vals[i] = __expf(vals[i] - mx);
    sm += vals[i];
  }
  for (int m = 1; m < 64; m <<= 1) sm += __shfl_xor(sm, m);
  if (lane == 0) rsum[w] = sm;
  __syncthreads();
  sm = rsum[0] + rsum[1] + rsum[2] + rsum[3];
  float inv = 1.f / sm;
  for (int i = 0; i < 8; i++) attn[(size_t)b * Sc + t + i * 256] = vals[i] * inv;
}

// ---- kernel 6: context partials from bf16 enc (half the traffic of fp32)
__global__ __launch_bounds__(256) void k_ctx(const unsigned short* __restrict__ ebf,
                                             const float* __restrict__ attn,
                                             const int* __restrict__ lengths,
                                             float* __restrict__ pctx) {
  int b = blockIdx.x >> 4, sp = blockIdx.x & 15;
  int t = threadIdx.x;
  int d0 = t * 4;
  int sbeg = sp * 128;
  float* outp = pctx + ((size_t)sp * Bc + b) * Dc + d0;
  int len = lengths[b];
  if (sbeg >= len) {
    *(float4*)outp = make_float4(0.f, 0.f, 0.f, 0.f);
    return;
  }
  __shared__ float at_s[128];
  if (t < 128) at_s[t] = attn[(size_t)b * Sc + sbeg + t];
  __syncthreads();
  float4 a = make_float4(0.f, 0.f, 0.f, 0.f);
  const unsigned short* ebase = ebf + ((size_t)b * Sc + sbeg) * Dc + d0;
  int ns = min(128, len - sbeg);
  for (int i = 0; i < ns; i++) {
    float wt = at_s[i];
    uint2 u = *(const uint2*)(ebase + (size_t)i * Dc);
    a.x += wt * __uint_as_float(u.x << 16);
    a.y += wt * __uint_as_float(u.x & 0xffff0000u);
    a.z += wt * __uint_as_float(u.y << 16);
    a.w += wt * __uint_as_float(u.y & 0xffff0000u);
  }
  *(float4*)outp = a;
}

// ---- kernel 7: reduce 16 context partials -> out (B,1,D)
__global__ __launch_bounds__(256) void k_reduce(const float* __restrict__ pctx,
                                               float* __restrict__ out) {
  int i = blockIdx.x * 256 + threadIdx.x;
  int b = i >> 10, d = i & 1023;
  float s = 0.f;
  for (int p = 0; p < 16; p++) s += pctx[((size_t)p * Bc + b) * Dc + d];
  out[i] = s;
}

extern "C" void kernel_launch(void* const* d_in, const int* in_sizes, int n_in,
                              void* d_out, int out_size, void* d_ws, size_t ws_size,
                              hipStream_t stream) {
  const float* enc = (const float*)d_in[0];
  const float* hidden = (const float*)d_in[1];
  const int* lengths = (const int*)d_in[2];
  const float* W = (const float*)d_in[3];
  const float* bias = (const float*)d_in[4];
  const float* v = (const float*)d_in[5];
  float* out = (float*)d_out;

  char* ws = (char*)d_ws;
  unsigned short* ebf = (unsigned short*)ws;
  unsigned short* webf = (unsigned short*)(ws + 67108864);
  float* hp = (float*)(ws + 69206016);
  float* pscores = (float*)(ws + 69271552);
  float* attn = (float*)(ws + 70320128);
  float* pctx = (float*)(ws + 70451200);
  int* wl = (int*)(ws + 70516736);  // wl[0..256] worklist

  hipLaunchKernelGGL(k_cvt_enc, dim3(2048), dim3(256), 0, stream, enc, ebf, lengths);
  hipLaunchKernelGGL(k_cvt_We, dim3(512), dim3(256), 0, stream, W, webf);
  hipLaunchKernelGGL(k_hidproj, dim3(1024), dim3(256), 0, stream, hidden, W, bias, hp);
  hipLaunchKernelGGL(k_worklist, dim3(1), dim3(256), 0, stream, lengths, wl);
  hipLaunchKernelGGL(k_scores, dim3(1024), dim3(256), 0, stream, ebf, webf, hp, v,
                     wl, pscores);
  hipLaunchKernelGGL(k_softmax, dim3(16), dim3(256), 0, stream, pscores, lengths, attn);
  hipLaunchKernelGGL(k_ctx, dim3(256), dim3(256), 0, stream, ebf, attn, lengths, pctx);
  hipLaunchKernelGGL(k_reduce, dim3(64), dim3(256), 0, stream, pctx, out);
}

// Round 9
// 111.326 us; speedup vs baseline: 1.2588x; 1.0508x over previous
//
#include <hip/hip_runtime.h>
#include <cstdint>

#define DEV static __device__ __forceinline__

typedef __attribute__((__ext_vector_type__(8))) __bf16 bf16x8;
typedef __attribute__((__ext_vector_type__(4))) float f32x4;

static constexpr int Bc = 16, Sc = 2048, Dc = 1024;

DEV unsigned short f2bf(float x) {
  unsigned int u = __float_as_uint(x);
  unsigned int r = (u + 0x7fffu + ((u >> 16) & 1u)) >> 16;
  return (unsigned short)r;
}
DEV unsigned int pack2(float a, float b) {
  return (unsigned int)f2bf(a) | ((unsigned int)f2bf(b) << 16);
}
DEV float tanh_fast(float x) {
  return 1.f - 2.f / (__expf(2.f * x) + 1.f);
}
DEV void gload16(const void* g, void* l) {
  __builtin_amdgcn_global_load_lds(
      (const __attribute__((address_space(1))) unsigned int*)g,
      (__attribute__((address_space(3))) unsigned int*)l, 16, 0, 0);
}

// ---- kernel 1: enc fp32 -> bf16, skipping masked rows (s >= len[b]).
__global__ __launch_bounds__(256) void k_cvt_enc(const float* __restrict__ in,
                                                 unsigned short* __restrict__ out,
                                                 const int* __restrict__ lengths) {
  int team = threadIdx.x >> 7;  // 0..1
  int lane = threadIdx.x & 127;
  int r0 = blockIdx.x * 16;
  int b = r0 >> 11;
  int len = lengths[b];
  for (int rr = team; rr < 16; rr += 2) {
    int s = (r0 + rr) & 2047;
    if (s >= len) continue;
    const float* src = in + (size_t)(r0 + rr) * Dc + lane * 8;
    unsigned short* dst = out + (size_t)(r0 + rr) * Dc + lane * 8;
    float4 f0 = *(const float4*)src;
    float4 f1 = *(const float4*)(src + 4);
    uint4 o;
    o.x = pack2(f0.x, f0.y);
    o.y = pack2(f0.z, f0.w);
    o.z = pack2(f1.x, f1.y);
    o.w = pack2(f1.z, f1.w);
    *(uint4*)dst = o;
  }
}

// ---- kernel 2: We[e,d] = W[e, D+d] -> bf16 (2 MB out)
__global__ __launch_bounds__(256) void k_cvt_We(const float* __restrict__ W,
                                                unsigned short* __restrict__ out) {
  int i = (blockIdx.x * 256 + threadIdx.x) * 8;
  int e = i >> 10, d = i & 1023;
  const float* p = W + (size_t)e * 2048 + 1024 + d;
  float4 f0 = *(const float4*)p;
  float4 f1 = *(const float4*)(p + 4);
  uint4 o;
  o.x = pack2(f0.x, f0.y);
  o.y = pack2(f0.z, f0.w);
  o.z = pack2(f1.x, f1.y);
  o.w = pack2(f1.z, f1.w);
  *(uint4*)(out + i) = o;
}

// ---- kernel 3: hid_proj[b,e] = bias[e] + sum_d hidden[b,d]*W[e,d]
__global__ __launch_bounds__(256) void k_hidproj(const float* __restrict__ hidden,
                                                 const float* __restrict__ W,
                                                 const float* __restrict__ bias,
                                                 float* __restrict__ hp) {
  __shared__ float wrow[Dc];
  int e = blockIdx.x, t = threadIdx.x;
  for (int i = t; i < Dc; i += 256) wrow[i] = W[(size_t)e * 2048 + i];
  __syncthreads();
  int w = t >> 6, lane = t & 63;
  float bv = bias[e];
  for (int bi = w; bi < Bc; bi += 4) {
    float s = 0.f;
    const float* hrow = hidden + (size_t)bi * Dc;
    for (int d = lane; d < Dc; d += 64) s += hrow[d] * wrow[d];
    for (int m = 1; m < 64; m <<= 1) s += __shfl_xor(s, m);
    if (lane == 0) hp[(size_t)bi * Dc + e] = s + bv;
  }
}

// ---- kernel 3b: compact active panels into a worklist (1 block).
// wl[0] = count; wl[1+i] = (b<<8)|sblk, sblk-major order (mixes batches).
__global__ __launch_bounds__(256) void k_worklist(const int* __restrict__ lengths,
                                                  int* __restrict__ wl) {
  int t = threadIdx.x;  // t = sblk*16 + b
  int sblk = t >> 4, b = t & 15;
  int active = (sblk * 128 < lengths[b]) ? 1 : 0;
  unsigned long long mask = __ballot(active);
  int lane = t & 63, wid = t >> 6;
  int prefix = __popcll(mask & ((1ull << lane) - 1ull));
  __shared__ int woff[4];
  if (lane == 0) woff[wid] = __popcll(mask);
  __syncthreads();
  int base = 0;
  for (int i = 0; i < wid; i++) base += woff[i];
  if (active) wl[1 + base + prefix] = (b << 8) | sblk;
  if (t == 0) wl[0] = woff[0] + woff[1] + woff[2] + woff[3];
}

// ---- kernel 4: scores GEMM (bf16 MFMA) + tanh + v-dot, per-e-tile partials.
// Round-6 config (worklist compaction, g=bx&255/et=bx>>8 -> XCD affinity)
// with TRUE counted-vmcnt double-buffering (T4): static buffers As0/As1,
// raw s_barrier + `s_waitcnt vmcnt(4)` so each wave waits only for its own
// 4 current-tile loads while next-tile loads stay in flight ACROSS the
// barriers (never drained to 0 in the main loop). __syncthreads was the
// round-3/4 failure: it emits vmcnt(0) and drains the prefetch.
__global__ __launch_bounds__(256) void k_scores(const unsigned short* __restrict__ Ae,
                                                const unsigned short* __restrict__ We,
                                                const float* __restrict__ hp,
                                                const float* __restrict__ v,
                                                const int* __restrict__ wl,
                                                float* __restrict__ pscores) {
  int g = blockIdx.x & 255;
  int et = blockIdx.x >> 8;
  if (g >= wl[0]) return;
  int pk = wl[1 + g];
  int b = pk >> 8, sblk = pk & 255;
  int s0 = sblk * 128;
  int m0 = b * Sc + s0;
  int e0 = et * 128;

  __shared__ unsigned short As0[128 * 32];
  __shared__ unsigned short As1[128 * 32];
  __shared__ unsigned short Bs0[128 * 32];
  __shared__ unsigned short Bs1[128 * 32];
  __shared__ float hp_s[128], v_s[128], sc_s[128];

  int t = threadIdx.x;
  int w = t >> 6, lane = t & 63;
  if (t < 128) {
    hp_s[t] = hp[(size_t)b * Dc + e0 + t];
    v_s[t] = v[e0 + t];
    sc_s[t] = 0.f;
  }
  // Drain the hp/v prologue loads so vmcnt counting below is exact.
  asm volatile("s_waitcnt vmcnt(0)" ::: "memory");

  f32x4 acc[4][4] = {};
  int wr = w >> 1, wc = w & 1;
  const unsigned short* ga0 = Ae + (size_t)(m0 + (t >> 2)) * Dc + (t & 3) * 8;
  const unsigned short* gb0 = We + (size_t)(e0 + (t >> 2)) * Dc + (t & 3) * 8;

  int kc = (lane >> 4) * 8;
  int ar = (wr * 64 + (lane & 15)) * 32 + kc;
  int br = (wc * 64 + (lane & 15)) * 32 + kc;

  // 4 VMEM instructions per wave per stage call.
  auto stage = [&](int k0, unsigned short* A, unsigned short* B) {
    gload16(ga0 + k0, A + w * 512);
    gload16(ga0 + k0 + 64 * Dc, A + 2048 + w * 512);
    gload16(gb0 + k0, B + w * 512);
    gload16(gb0 + k0 + 64 * Dc, B + 2048 + w * 512);
  };
  auto compute = [&](const unsigned short* A, const unsigned short* B) {
    bf16x8 af[4], bfr[4];
#pragma unroll
    for (int m = 0; m < 4; m++)
      af[m] = __builtin_bit_cast(bf16x8, *(const uint4*)(A + ar + m * 512));
#pragma unroll
    for (int n = 0; n < 4; n++)
      bfr[n] = __builtin_bit_cast(bf16x8, *(const uint4*)(B + br + n * 512));
#pragma unroll
    for (int m = 0; m < 4; m++)
#pragma unroll
      for (int n = 0; n < 4; n++)
        acc[m][n] = __builtin_amdgcn_mfma_f32_16x16x32_bf16(af[m], bfr[n], acc[m][n], 0, 0, 0);
  };

  stage(0, As0, Bs0);  // 4 outstanding

#pragma unroll 1
  for (int i2 = 0; i2 < 15; ++i2) {
    // phase A: prefetch odd tile, compute even tile
    stage((2 * i2 + 1) * 32, As1, Bs1);                // 8 outstanding
    asm volatile("s_waitcnt vmcnt(4)" ::: "memory");   // even tile landed
    __builtin_amdgcn_sched_barrier(0);
    __builtin_amdgcn_s_barrier();                      // all waves: tile ready
    __builtin_amdgcn_sched_barrier(0);
    compute(As0, Bs0);
    __builtin_amdgcn_sched_barrier(0);
    __builtin_amdgcn_s_barrier();                      // all waves done reading
    // phase B: prefetch even tile (buffer just freed), compute odd tile
    stage((2 * i2 + 2) * 32, As0, Bs0);
    asm volatile("s_waitcnt vmcnt(4)" ::: "memory");
    __builtin_amdgcn_sched_barrier(0);
    __builtin_amdgcn_s_barrier();
    __builtin_amdgcn_sched_barrier(0);
    compute(As1, Bs1);
    __builtin_amdgcn_sched_barrier(0);
    __builtin_amdgcn_s_barrier();
  }
  // tail: tile 30 is in As0/Bs0; stage tile 31, compute both.
  stage(31 * 32, As1, Bs1);
  asm volatile("s_waitcnt vmcnt(4)" ::: "memory");
  __builtin_amdgcn_sched_barrier(0);
  __builtin_amdgcn_s_barrier();
  __builtin_amdgcn_sched_barrier(0);
  compute(As0, Bs0);
  __builtin_amdgcn_sched_barrier(0);
  __builtin_amdgcn_s_barrier();
  asm volatile("s_waitcnt vmcnt(0)" ::: "memory");
  __builtin_amdgcn_sched_barrier(0);
  __builtin_amdgcn_s_barrier();
  __builtin_amdgcn_sched_barrier(0);
  compute(As1, Bs1);

  // epilogue: rowsum_e( v[e] * tanh(acc + hp[e]) )
  for (int m = 0; m < 4; m++) {
    float rs0 = 0.f, rs1 = 0.f, rs2 = 0.f, rs3 = 0.f;
    for (int n = 0; n < 4; n++) {
      int ec = wc * 64 + n * 16 + (lane & 15);
      float hpv = hp_s[ec], vv = v_s[ec];
      f32x4 a = acc[m][n];
      rs0 += vv * tanh_fast(a[0] + hpv);
      rs1 += vv * tanh_fast(a[1] + hpv);
      rs2 += vv * tanh_fast(a[2] + hpv);
      rs3 += vv * tanh_fast(a[3] + hpv);
    }
    for (int mask = 1; mask < 16; mask <<= 1) {
      rs0 += __shfl_xor(rs0, mask);
      rs1 += __shfl_xor(rs1, mask);
      rs2 += __shfl_xor(rs2, mask);
      rs3 += __shfl_xor(rs3, mask);
    }
    if ((lane & 15) == 0) {  // exactly 2 adders per row (wc=0,1): deterministic
      int rbase = wr * 64 + m * 16 + (lane >> 4) * 4;
      atomicAdd(&sc_s[rbase + 0], rs0);
      atomicAdd(&sc_s[rbase + 1], rs1);
      atomicAdd(&sc_s[rbase + 2], rs2);
      atomicAdd(&sc_s[rbase + 3], rs3);
    }
  }
  __syncthreads();
  if (t < 128) pscores[((size_t)et * Bc + b) * Sc + s0 + t] = sc_s[t];
}

// ---- kernel 5: masked softmax over S per batch; sums 8 e-tile partials
__global__ __launch_bounds__(256) void k_softmax(const float* __restrict__ pscores,
                                                 const int* __restrict__ lengths,
                                                 float* __restrict__ attn) {
  int b = blockIdx.x, t = threadIdx.x;
  int len = lengths[b];
  float vals[8];
  float mx = -INFINITY;
  for (int i = 0; i < 8; i++) {
    int s = t + i * 256;
    float sc = 0.f;
    for (int p = 0; p < 8; p++) sc += pscores[((size_t)p * Bc + b) * Sc + s];
    sc = (s < len) ? sc : -INFINITY;
    vals[i] = sc;
    mx = fmaxf(mx, sc);
  }
  for (int m = 1; m < 64; m <<= 1) mx = fmaxf(mx, __shfl_xor(mx, m));
  __shared__ float rmax[4], rsum[4];
  int w = t >> 6, lane = t & 63;
  if (lane == 0) rmax[w] = mx;
  __syncthreads();
  mx = fmaxf(fmaxf(rmax[0], rmax[1]), fmaxf(rmax[2], rmax[3]));
  float sm = 0.f;
  for (int i = 0; i < 8; i++) {
    vals[i] = __expf(vals[i] - mx);
    sm += vals[i];
  }
  for (int m = 1; m < 64; m <<= 1) sm += __shfl_xor(sm, m);
  if (lane == 0) rsum[w] = sm;
  __syncthreads();
  sm = rsum[0] + rsum[1] + rsum[2] + rsum[3];
  float inv = 1.f / sm;
  for (int i = 0; i < 8; i++) attn[(size_t)b * Sc + t + i * 256] = vals[i] * inv;
}

// ---- kernel 6: context partials from bf16 enc (half the traffic of fp32)
__global__ __launch_bounds__(256) void k_ctx(const unsigned short* __restrict__ ebf,
                                             const float* __restrict__ attn,
                                             const int* __restrict__ lengths,
                                             float* __restrict__ pctx) {
  int b = blockIdx.x >> 4, sp = blockIdx.x & 15;
  int t = threadIdx.x;
  int d0 = t * 4;
  int sbeg = sp * 128;
  float* outp = pctx + ((size_t)sp * Bc + b) * Dc + d0;
  int len = lengths[b];
  if (sbeg >= len) {
    *(float4*)outp = make_float4(0.f, 0.f, 0.f, 0.f);
    return;
  }
  __shared__ float at_s[128];
  if (t < 128) at_s[t] = attn[(size_t)b * Sc + sbeg + t];
  __syncthreads();
  float4 a = make_float4(0.f, 0.f, 0.f, 0.f);
  const unsigned short* ebase = ebf + ((size_t)b * Sc + sbeg) * Dc + d0;
  int ns = min(128, len - sbeg);
  for (int i = 0; i < ns; i++) {
    float wt = at_s[i];
    uint2 u = *(const uint2*)(ebase + (size_t)i * Dc);
    a.x += wt * __uint_as_float(u.x << 16);
    a.y += wt * __uint_as_float(u.x & 0xffff0000u);
    a.z += wt * __uint_as_float(u.y << 16);
    a.w += wt * __uint_as_float(u.y & 0xffff0000u);
  }
  *(float4*)outp = a;
}

// ---- kernel 7: reduce 16 context partials -> out (B,1,D)
__global__ __launch_bounds__(256) void k_reduce(const float* __restrict__ pctx,
                                               float* __restrict__ out) {
  int i = blockIdx.x * 256 + threadIdx.x;
  int b = i >> 10, d = i & 1023;
  float s = 0.f;
  for (int p = 0; p < 16; p++) s += pctx[((size_t)p * Bc + b) * Dc + d];
  out[i] = s;
}

extern "C" void kernel_launch(void* const* d_in, const int* in_sizes, int n_in,
                              void* d_out, int out_size, void* d_ws, size_t ws_size,
                              hipStream_t stream) {
  const float* enc = (const float*)d_in[0];
  const float* hidden = (const float*)d_in[1];
  const int* lengths = (const int*)d_in[2];
  const float* W = (const float*)d_in[3];
  const float* bias = (const float*)d_in[4];
  const float* v = (const float*)d_in[5];
  float* out = (float*)d_out;

  char* ws = (char*)d_ws;
  unsigned short* ebf = (unsigned short*)ws;
  unsigned short* webf = (unsigned short*)(ws + 67108864);
  float* hp = (float*)(ws + 69206016);
  float* pscores = (float*)(ws + 69271552);
  float* attn = (float*)(ws + 70320128);
  float* pctx = (float*)(ws + 70451200);
  int* wl = (int*)(ws + 70516736);  // wl[0..256] worklist

  hipLaunchKernelGGL(k_cvt_enc, dim3(2048), dim3(256), 0, stream, enc, ebf, lengths);
  hipLaunchKernelGGL(k_cvt_We, dim3(512), dim3(256), 0, stream, W, webf);
  hipLaunchKernelGGL(k_hidproj, dim3(1024), dim3(256), 0, stream, hidden, W, bias, hp);
  hipLaunchKernelGGL(k_worklist, dim3(1), dim3(256), 0, stream, lengths, wl);
  hipLaunchKernelGGL(k_scores, dim3(2048), dim3(256), 0, stream, ebf, webf, hp, v,
                     wl, pscores);
  hipLaunchKernelGGL(k_softmax, dim3(16), dim3(256), 0, stream, pscores, lengths, attn);
  hipLaunchKernelGGL(k_ctx, dim3(256), dim3(256), 0, stream, ebf, attn, lengths, pctx);
  hipLaunchKernelGGL(k_reduce, dim3(64), dim3(256), 0, stream, pctx, out);
}